// Round 7
// baseline (175.080 us; speedup 1.0000x reference)
//
#include <hip/hip_runtime.h>
#include <math.h>

#define S_LEN 2048
#define DHEAD 128
#define NHEAD 16
#define QBLK  128                      // per phase: 4 waves x 32 q-rows
#define KVBLK 64
#define ATT_SCALE 0.08838834764831845f // 1/sqrt(128)
#define LOG2E 1.4426950408889634f
#define SHIFT2 11.5f                   // fixed softmax shift in log2 units

#define KP 136                         // K tile pitch (bf16 elems)
#define VP 72                          // V^T tile pitch

typedef __attribute__((ext_vector_type(4))) float f32x4;
typedef __attribute__((ext_vector_type(8))) short s16x8;
typedef __attribute__((ext_vector_type(2))) int   i32x2;

// RNE f32 pair -> packed bf16 dword (T12 recipe; no builtin on gfx950)
__device__ __forceinline__ int pk2(float lo, float hi) {
  int d;
  asm("v_cvt_pk_bf16_f32 %0, %1, %2" : "=v"(d) : "v"(lo), "v"(hi));
  return d;
}

// pi(j) = 32*(j>>5) + 8*((j>>2)&3) + 4*((j>>4)&1) + (j&3): bijective kv-slot
// permutation applied to BOTH V^T staging slots and the pa pack order, so it
// cancels inside the PV dot product. It makes a lane's 8 in-register P values
// (nt pair x r) exactly one contiguous A-fragment k-chunk.

__global__ __launch_bounds__(256, 2)
void alibi_attn_fwd(const float* __restrict__ Qg, const float* __restrict__ Kg,
                    const float* __restrict__ Vg, float* __restrict__ Og)
{
  __shared__ __align__(16) short kt[2][KVBLK * KP];   // K tiles [buf][kv][d]
  __shared__ __align__(16) short vt[2][DHEAD * VP];   // V^T tiles [buf][d][pi(kv)]

  const int tid  = threadIdx.x;
  const int lane = tid & 63;
  const int w    = tid >> 6;      // wave 0..3, owns 32 q-rows per phase
  const int l16  = lane & 15;
  const int lg   = lane >> 4;     // 0..3

  // n = pr*64 + bh: XCD = n&7 = bh&7 (head-local L2). Each block runs q-tile
  // pair {15-pr, pr}: uniform 34 kv-tiles for every block.
  const int n    = blockIdx.x;
  const int bh   = n & 63;
  const int pr   = n >> 6;
  const int head = bh & (NHEAD - 1);

  const size_t base = (size_t)bh * S_LEN * DHEAD;
  const float* Q = Qg + base;
  const float* K = Kg + base;
  const float* V = Vg + base;
  float*       O = Og + base;

  const float slope2 = exp2f(-0.5f * (float)(head + 1)) * LOG2E;
  float cn16[4], rsv[4];
  #pragma unroll
  for (int x = 0; x < 4; ++x) { cn16[x] = (float)(16 * x) * slope2; rsv[x] = (float)x * slope2; }

  s16x8 ones;
  #pragma unroll
  for (int jj = 0; jj < 8; ++jj) ones[jj] = (short)0x3f80;  // bf16 1.0

  const f32x4 zero4 = {0.f, 0.f, 0.f, 0.f};

  const int qt0 = 15 - pr, qt1 = pr;
  const int qb0 = qt0 * QBLK, qb1 = qt1 * QBLK;
  const int n0 = 2 * (qt0 + 1);
  const int NT = n0 + 2 * (qt1 + 1);   // 34 for all blocks

  // ---- staging maps (256 threads) ----
  // K: row kr (0..63), d = kd0..kd0+31
  const int kr  = tid >> 2;
  const int kd0 = 32 * (tid & 3);
  // V: rows Rv..Rv+3, d = d0v..d0v+7 -> 8 b64 writes at pi slots vslotb..+3
  const int grp = tid & 15;
  const int vnt = grp >> 2, vg = grp & 3;
  const int Rv  = 16 * vnt + 4 * vg;
  const int d0v = 8 * (tid >> 4);
  const int vslotb = 32 * (vnt >> 1) + 8 * vg + 4 * (vnt & 1);

  f32x4 ka[8], va[8];   // prefetch regs (tile in flight)

#define LOAD_TILE(KV0) do {                                            \
    const float* kp_ = K + (size_t)((KV0) + kr) * DHEAD + kd0;         \
    ka[0] = *(const f32x4*)(kp_);      ka[1] = *(const f32x4*)(kp_ + 4);   \
    ka[2] = *(const f32x4*)(kp_ + 8);  ka[3] = *(const f32x4*)(kp_ + 12);  \
    ka[4] = *(const f32x4*)(kp_ + 16); ka[5] = *(const f32x4*)(kp_ + 20);  \
    ka[6] = *(const f32x4*)(kp_ + 24); ka[7] = *(const f32x4*)(kp_ + 28);  \
    const float* vp_ = V + (size_t)((KV0) + Rv) * DHEAD + d0v;         \
    va[0] = *(const f32x4*)(vp_);             va[1] = *(const f32x4*)(vp_ + 4);           \
    va[2] = *(const f32x4*)(vp_ + DHEAD);     va[3] = *(const f32x4*)(vp_ + DHEAD + 4);   \
    va[4] = *(const f32x4*)(vp_ + 2*DHEAD);   va[5] = *(const f32x4*)(vp_ + 2*DHEAD + 4); \
    va[6] = *(const f32x4*)(vp_ + 3*DHEAD);   va[7] = *(const f32x4*)(vp_ + 3*DHEAD + 4); \
  } while (0)

#define STORE_TILE(BUF) do {                                           \
    short* ktp = &kt[BUF][kr * KP + kd0];                              \
    _Pragma("unroll")                                                  \
    for (int h = 0; h < 4; ++h) {                                      \
      union { int d[4]; s16x8 v; } uu;                                 \
      uu.d[0] = pk2(ka[2*h][0],   ka[2*h][1]);                         \
      uu.d[1] = pk2(ka[2*h][2],   ka[2*h][3]);                         \
      uu.d[2] = pk2(ka[2*h+1][0], ka[2*h+1][1]);                       \
      uu.d[3] = pk2(ka[2*h+1][2], ka[2*h+1][3]);                       \
      *(s16x8*)(ktp + 8*h) = uu.v;                                     \
    }                                                                  \
    _Pragma("unroll")                                                  \
    for (int e = 0; e < 8; ++e) {                                      \
      i32x2 dv;                                                        \
      dv[0] = pk2(va[(e>>2)][e&3],     va[2+(e>>2)][e&3]);             \
      dv[1] = pk2(va[4+(e>>2)][e&3],   va[6+(e>>2)][e&3]);             \
      *(i32x2*)&vt[BUF][(d0v + e) * VP + vslotb] = dv;                 \
    }                                                                  \
  } while (0)

  // ---- per-phase state ----
  s16x8 qf[2][4];
  f32x4 oacc[2][8], lacc[2];
  int   iq0 = 0;
  int   qb  = qb0;

  auto init_phase = [&](int qbn) {
    qb  = qbn;
    iq0 = qbn + 32 * w + l16;
    #pragma unroll
    for (int m = 0; m < 2; ++m) {
      const float* qp = Q + (size_t)(qbn + 32*w + 16*m + l16) * DHEAD + 8*lg;
      #pragma unroll
      for (int c = 0; c < 4; ++c) {
        f32x4 a = *(const f32x4*)(qp + 32*c);
        f32x4 b = *(const f32x4*)(qp + 32*c + 4);
        const float sc = ATT_SCALE * LOG2E;
        union { int d[4]; s16x8 v; } uu;
        uu.d[0] = pk2(a[0]*sc, a[1]*sc); uu.d[1] = pk2(a[2]*sc, a[3]*sc);
        uu.d[2] = pk2(b[0]*sc, b[1]*sc); uu.d[3] = pk2(b[2]*sc, b[3]*sc);
        qf[m][c] = uu.v;
      }
      #pragma unroll
      for (int dt = 0; dt < 8; ++dt) oacc[m][dt] = zero4;
      lacc[m] = zero4;
    }
  };

  auto epilogue = [&](int qbn) {
    #pragma unroll
    for (int m = 0; m < 2; ++m) {
      #pragma unroll
      for (int r = 0; r < 4; ++r) {
        const float inv = 1.0f / lacc[m][r];
        float* op = O + (size_t)(qbn + 32*w + 16*m + 4*lg + r) * DHEAD + l16;
        #pragma unroll
        for (int dt = 0; dt < 8; ++dt) op[dt * 16] = oacc[m][dt][r] * inv;
      }
    }
  };

  init_phase(qb0);
  LOAD_TILE(0);
  STORE_TILE(0);
  LOAD_TILE(KVBLK);          // NT >= 18 in phase 0, always valid
  __syncthreads();

  for (int s = 0; s < NT; ++s) {
    if (s == n0) { epilogue(qb0); init_phase(qb1); }
    const int cur = s & 1;
    if (s + 1 < NT) STORE_TILE((s + 1) & 1);     // regs -> other buffer
    if (s + 2 < NT) {
      const int s2 = s + 2;
      LOAD_TILE(((s2 < n0) ? s2 : s2 - n0) * KVBLK);   // full-iter prefetch
    }
    const int kv0 = ((s < n0) ? s : s - n0) * KVBLK;

    if (kv0 <= qb + 32 * w + 31) {
      const short* ktc = kt[cur];
      const short* vtc = vt[cur];

      // ---- QK^T swapped: sacc = K * Q^T -> q-row = l16, kv in-register ----
      f32x4 sacc[2][4];
      #pragma unroll
      for (int nt = 0; nt < 4; ++nt) { sacc[0][nt] = zero4; sacc[1][nt] = zero4; }
      __builtin_amdgcn_s_setprio(1);
      #pragma unroll
      for (int c = 0; c < 4; ++c) {
        #pragma unroll
        for (int nt = 0; nt < 4; ++nt) {
          s16x8 kf = *(const s16x8*)&ktc[(nt*16 + l16) * KP + 32*c + 8*lg];
          sacc[0][nt] = __builtin_amdgcn_mfma_f32_16x16x32_bf16(kf, qf[0][c], sacc[0][nt], 0, 0, 0);
          sacc[1][nt] = __builtin_amdgcn_mfma_f32_16x16x32_bf16(kf, qf[1][c], sacc[1][nt], 0, 0, 0);
        }
      }
      __builtin_amdgcn_s_setprio(0);

      // ---- softmax in-register: p = 2^(s + (j-i)*slope2 - SHIFT2) ----
      const bool needMask = (kv0 + KVBLK - 1 > qb + 32 * w);  // diagonal tile only
      s16x8 pa[2][2];
      #pragma unroll
      for (int m = 0; m < 2; ++m) {
        const int dji = kv0 + 4*lg - (iq0 + 16*m);   // j - i at (nt=0, r=0)
        const float b0m = (float)dji * slope2 - SHIFT2;
        float p[4][4];
        #pragma unroll
        for (int nt = 0; nt < 4; ++nt) {
          const float bmn = b0m + cn16[nt];
          #pragma unroll
          for (int r = 0; r < 4; ++r)
            p[nt][r] = __builtin_amdgcn_exp2f(sacc[m][nt][r] + bmn + rsv[r]);
        }
        if (needMask) {
          #pragma unroll
          for (int nt = 0; nt < 4; ++nt)
            #pragma unroll
            for (int r = 0; r < 4; ++r)
              if (dji + 16*nt + r > 0) p[nt][r] = 0.f;
        }
        #pragma unroll
        for (int c2 = 0; c2 < 2; ++c2) {
          union { int d[4]; s16x8 v; } uu;
          uu.d[0] = pk2(p[2*c2][0],   p[2*c2][1]);
          uu.d[1] = pk2(p[2*c2][2],   p[2*c2][3]);
          uu.d[2] = pk2(p[2*c2+1][0], p[2*c2+1][1]);
          uu.d[3] = pk2(p[2*c2+1][2], p[2*c2+1][3]);
          pa[m][c2] = uu.v;   // k-slots c2*32 + 8*lg .. +7 in pi space
        }
      }

      // ---- PV in pi space; row-sum via ones-MFMA ----
      __builtin_amdgcn_s_setprio(1);
      #pragma unroll
      for (int c2 = 0; c2 < 2; ++c2) {
        lacc[0] = __builtin_amdgcn_mfma_f32_16x16x32_bf16(pa[0][c2], ones, lacc[0], 0, 0, 0);
        lacc[1] = __builtin_amdgcn_mfma_f32_16x16x32_bf16(pa[1][c2], ones, lacc[1], 0, 0, 0);
        #pragma unroll
        for (int dt = 0; dt < 8; ++dt) {
          s16x8 bv = *(const s16x8*)&vtc[(dt*16 + l16) * VP + c2*32 + 8*lg];
          oacc[0][dt] = __builtin_amdgcn_mfma_f32_16x16x32_bf16(pa[0][c2], bv, oacc[0][dt], 0, 0, 0);
          oacc[1][dt] = __builtin_amdgcn_mfma_f32_16x16x32_bf16(pa[1][c2], bv, oacc[1][dt], 0, 0, 0);
        }
      }
      __builtin_amdgcn_s_setprio(0);
    }
    __syncthreads();
  }
  epilogue(qb1);
}

extern "C" void kernel_launch(void* const* d_in, const int* in_sizes, int n_in,
                              void* d_out, int out_size, void* d_ws, size_t ws_size,
                              hipStream_t stream) {
  (void)in_sizes; (void)n_in; (void)out_size; (void)d_ws; (void)ws_size;
  const float* q = (const float*)d_in[0];
  const float* k = (const float*)d_in[1];
  const float* v = (const float*)d_in[2];
  float* o = (float*)d_out;
  dim3 grid(512);    // 64 heads x 8 uniform q-tile pairs; 2 blocks/CU
  dim3 block(256);
  alibi_attn_fwd<<<grid, block, 0, stream>>>(q, k, v, o);
}

// Round 8
// 172.813 us; speedup vs baseline: 1.0131x; 1.0131x over previous
//
#include <hip/hip_runtime.h>
#include <math.h>

#define S_LEN 2048
#define DHEAD 128
#define NHEAD 16
#define QBLK  128                      // per phase: 4 waves x 32 q-rows
#define KVBLK 64
#define ATT_SCALE 0.08838834764831845f // 1/sqrt(128)
#define LOG2E 1.4426950408889634f
#define SHIFT2 11.5f                   // fixed softmax shift in log2 units

#define KP 136                         // K tile pitch (bf16 elems)
#define VP 72                          // V^T tile pitch

typedef __attribute__((ext_vector_type(4))) float f32x4;
typedef __attribute__((ext_vector_type(8))) short s16x8;
typedef __attribute__((ext_vector_type(2))) int   i32x2;

// RNE f32 pair -> packed bf16 dword (T12 recipe; no builtin on gfx950)
__device__ __forceinline__ int pk2(float lo, float hi) {
  int d;
  asm("v_cvt_pk_bf16_f32 %0, %1, %2" : "=v"(d) : "v"(lo), "v"(hi));
  return d;
}

// pi(j) = 32*(j>>5) + 8*((j>>2)&3) + 4*((j>>4)&1) + (j&3): bijective kv-slot
// permutation applied to BOTH V^T staging slots and the pa pack order, so it
// cancels inside the PV dot product. It makes a lane's 8 in-register P values
// exactly one contiguous A-fragment k-chunk.
//
// Single-buffered K/V (35.8 KB LDS) -> 4 blocks/CU x 4 waves = 16 waves/CU:
// inter-block co-scheduling hides the per-block serial staging chain (m114).

__global__ __launch_bounds__(256, 2)
void alibi_attn_fwd(const float* __restrict__ Qg, const float* __restrict__ Kg,
                    const float* __restrict__ Vg, float* __restrict__ Og)
{
  __shared__ __align__(16) short kt[KVBLK * KP];   // K tile [kv][d]
  __shared__ __align__(16) short vt[DHEAD * VP];   // V^T tile [d][pi(kv)]

  const int tid  = threadIdx.x;
  const int lane = tid & 63;
  const int w    = tid >> 6;      // wave 0..3, owns 32 q-rows per phase
  const int l16  = lane & 15;
  const int lg   = lane >> 4;     // 0..3

  // n = pr*64 + bh: XCD = n&7 = bh&7 (head-local L2). Each block runs q-tile
  // pair {15-pr, pr}: uniform 34 kv-tiles for every block.
  const int n    = blockIdx.x;
  const int bh   = n & 63;
  const int pr   = n >> 6;
  const int head = bh & (NHEAD - 1);

  const size_t base = (size_t)bh * S_LEN * DHEAD;
  const float* Q = Qg + base;
  const float* K = Kg + base;
  const float* V = Vg + base;
  float*       O = Og + base;

  const float slope2 = exp2f(-0.5f * (float)(head + 1)) * LOG2E;
  float cn16[4], rsv[4];
  #pragma unroll
  for (int x = 0; x < 4; ++x) { cn16[x] = (float)(16 * x) * slope2; rsv[x] = (float)x * slope2; }

  s16x8 ones;
  #pragma unroll
  for (int jj = 0; jj < 8; ++jj) ones[jj] = (short)0x3f80;  // bf16 1.0

  const f32x4 zero4 = {0.f, 0.f, 0.f, 0.f};

  const int qt0 = 15 - pr, qt1 = pr;
  const int qb0 = qt0 * QBLK, qb1 = qt1 * QBLK;
  const int n0 = 2 * (qt0 + 1);
  const int NT = n0 + 2 * (qt1 + 1);   // 34 for all blocks

  // ---- staging maps (256 threads) ----
  // K: row kr (0..63), d = kd0..kd0+31
  const int kr  = tid >> 2;
  const int kd0 = 32 * (tid & 3);
  // V: rows Rv..Rv+3, d = d0v..d0v+7 -> 8 b64 writes at pi slots vslotb..+3
  const int grp = tid & 15;
  const int vnt = grp >> 2, vg = grp & 3;
  const int Rv  = 16 * vnt + 4 * vg;
  const int d0v = 8 * (tid >> 4);
  const int vslotb = 32 * (vnt >> 1) + 8 * vg + 4 * (vnt & 1);

  f32x4 ka[8], va[8];   // T14 prefetch regs (tile in flight across compute)

#define LOAD_TILE(KV0) do {                                            \
    const float* kp_ = K + (size_t)((KV0) + kr) * DHEAD + kd0;         \
    ka[0] = *(const f32x4*)(kp_);      ka[1] = *(const f32x4*)(kp_ + 4);   \
    ka[2] = *(const f32x4*)(kp_ + 8);  ka[3] = *(const f32x4*)(kp_ + 12);  \
    ka[4] = *(const f32x4*)(kp_ + 16); ka[5] = *(const f32x4*)(kp_ + 20);  \
    ka[6] = *(const f32x4*)(kp_ + 24); ka[7] = *(const f32x4*)(kp_ + 28);  \
    const float* vp_ = V + (size_t)((KV0) + Rv) * DHEAD + d0v;         \
    va[0] = *(const f32x4*)(vp_);             va[1] = *(const f32x4*)(vp_ + 4);           \
    va[2] = *(const f32x4*)(vp_ + DHEAD);     va[3] = *(const f32x4*)(vp_ + DHEAD + 4);   \
    va[4] = *(const f32x4*)(vp_ + 2*DHEAD);   va[5] = *(const f32x4*)(vp_ + 2*DHEAD + 4); \
    va[6] = *(const f32x4*)(vp_ + 3*DHEAD);   va[7] = *(const f32x4*)(vp_ + 3*DHEAD + 4); \
  } while (0)

#define STORE_TILE() do {                                              \
    short* ktp = &kt[kr * KP + kd0];                                   \
    _Pragma("unroll")                                                  \
    for (int h = 0; h < 4; ++h) {                                      \
      union { int d[4]; s16x8 v; } uu;                                 \
      uu.d[0] = pk2(ka[2*h][0],   ka[2*h][1]);                         \
      uu.d[1] = pk2(ka[2*h][2],   ka[2*h][3]);                         \
      uu.d[2] = pk2(ka[2*h+1][0], ka[2*h+1][1]);                       \
      uu.d[3] = pk2(ka[2*h+1][2], ka[2*h+1][3]);                       \
      *(s16x8*)(ktp + 8*h) = uu.v;                                     \
    }                                                                  \
    _Pragma("unroll")                                                  \
    for (int e = 0; e < 8; ++e) {                                      \
      i32x2 dv;                                                        \
      dv[0] = pk2(va[(e>>2)][e&3],     va[2+(e>>2)][e&3]);             \
      dv[1] = pk2(va[4+(e>>2)][e&3],   va[6+(e>>2)][e&3]);             \
      *(i32x2*)&vt[(d0v + e) * VP + vslotb] = dv;                      \
    }                                                                  \
  } while (0)

  // ---- per-phase state ----
  s16x8 qf[2][4];
  f32x4 oacc[2][8], lacc[2];
  int   iq0 = 0;
  int   qb  = qb0;

  auto init_phase = [&](int qbn) {
    qb  = qbn;
    iq0 = qbn + 32 * w + l16;
    #pragma unroll
    for (int m = 0; m < 2; ++m) {
      const float* qp = Q + (size_t)(qbn + 32*w + 16*m + l16) * DHEAD + 8*lg;
      #pragma unroll
      for (int c = 0; c < 4; ++c) {
        f32x4 a = *(const f32x4*)(qp + 32*c);
        f32x4 b = *(const f32x4*)(qp + 32*c + 4);
        const float sc = ATT_SCALE * LOG2E;
        union { int d[4]; s16x8 v; } uu;
        uu.d[0] = pk2(a[0]*sc, a[1]*sc); uu.d[1] = pk2(a[2]*sc, a[3]*sc);
        uu.d[2] = pk2(b[0]*sc, b[1]*sc); uu.d[3] = pk2(b[2]*sc, b[3]*sc);
        qf[m][c] = uu.v;
      }
      #pragma unroll
      for (int dt = 0; dt < 8; ++dt) oacc[m][dt] = zero4;
      lacc[m] = zero4;
    }
  };

  auto epilogue = [&](int qbn) {
    #pragma unroll
    for (int m = 0; m < 2; ++m) {
      #pragma unroll
      for (int r = 0; r < 4; ++r) {
        const float inv = 1.0f / lacc[m][r];
        float* op = O + (size_t)(qbn + 32*w + 16*m + 4*lg + r) * DHEAD + l16;
        #pragma unroll
        for (int dt = 0; dt < 8; ++dt) op[dt * 16] = oacc[m][dt][r] * inv;
      }
    }
  };

  init_phase(qb0);
  LOAD_TILE(0);

  for (int s = 0; s < NT; ++s) {
    if (s == n0) { epilogue(qb0); init_phase(qb1); }

    if (s) __syncthreads();        // all waves done reading previous tile
    STORE_TILE();                  // drains prefetch regs (vmcnt) -> LDS
    __syncthreads();               // tile visible

    if (s + 1 < NT) {              // issue next tile's loads (T14)
      const int s1 = s + 1;
      LOAD_TILE(((s1 < n0) ? s1 : s1 - n0) * KVBLK);
    }

    const int kv0 = ((s < n0) ? s : s - n0) * KVBLK;

    if (kv0 <= qb + 32 * w + 31) {
      // ---- QK^T swapped: sacc = K * Q^T -> q-row = l16, kv in-register ----
      f32x4 sacc[2][4];
      #pragma unroll
      for (int nt = 0; nt < 4; ++nt) { sacc[0][nt] = zero4; sacc[1][nt] = zero4; }
      __builtin_amdgcn_s_setprio(1);
      #pragma unroll
      for (int c = 0; c < 4; ++c) {
        #pragma unroll
        for (int nt = 0; nt < 4; ++nt) {
          s16x8 kf = *(const s16x8*)&kt[(nt*16 + l16) * KP + 32*c + 8*lg];
          sacc[0][nt] = __builtin_amdgcn_mfma_f32_16x16x32_bf16(kf, qf[0][c], sacc[0][nt], 0, 0, 0);
          sacc[1][nt] = __builtin_amdgcn_mfma_f32_16x16x32_bf16(kf, qf[1][c], sacc[1][nt], 0, 0, 0);
        }
      }
      __builtin_amdgcn_s_setprio(0);

      // ---- softmax in-register: p = 2^(s + (j-i)*slope2 - SHIFT2) ----
      const bool needMask = (kv0 + KVBLK - 1 > qb + 32 * w);  // diagonal tiles only
      s16x8 pa[2][2];
      #pragma unroll
      for (int m = 0; m < 2; ++m) {
        const int dji = kv0 + 4*lg - (iq0 + 16*m);   // j - i at (nt=0, r=0)
        const float b0m = (float)dji * slope2 - SHIFT2;
        float p[4][4];
        #pragma unroll
        for (int nt = 0; nt < 4; ++nt) {
          const float bmn = b0m + cn16[nt];
          #pragma unroll
          for (int r = 0; r < 4; ++r)
            p[nt][r] = __builtin_amdgcn_exp2f(sacc[m][nt][r] + bmn + rsv[r]);
        }
        if (needMask) {
          #pragma unroll
          for (int nt = 0; nt < 4; ++nt)
            #pragma unroll
            for (int r = 0; r < 4; ++r)
              if (dji + 16*nt + r > 0) p[nt][r] = 0.f;
        }
        #pragma unroll
        for (int c2 = 0; c2 < 2; ++c2) {
          union { int d[4]; s16x8 v; } uu;
          uu.d[0] = pk2(p[2*c2][0],   p[2*c2][1]);
          uu.d[1] = pk2(p[2*c2][2],   p[2*c2][3]);
          uu.d[2] = pk2(p[2*c2+1][0], p[2*c2+1][1]);
          uu.d[3] = pk2(p[2*c2+1][2], p[2*c2+1][3]);
          pa[m][c2] = uu.v;   // k-slots c2*32 + 8*lg .. +7 in pi space
        }
      }

      // ---- PV in pi space; row-sum via ones-MFMA ----
      __builtin_amdgcn_s_setprio(1);
      #pragma unroll
      for (int c2 = 0; c2 < 2; ++c2) {
        lacc[0] = __builtin_amdgcn_mfma_f32_16x16x32_bf16(pa[0][c2], ones, lacc[0], 0, 0, 0);
        lacc[1] = __builtin_amdgcn_mfma_f32_16x16x32_bf16(pa[1][c2], ones, lacc[1], 0, 0, 0);
        #pragma unroll
        for (int dt = 0; dt < 8; ++dt) {
          s16x8 bv = *(const s16x8*)&vt[(dt*16 + l16) * VP + c2*32 + 8*lg];
          oacc[0][dt] = __builtin_amdgcn_mfma_f32_16x16x32_bf16(pa[0][c2], bv, oacc[0][dt], 0, 0, 0);
          oacc[1][dt] = __builtin_amdgcn_mfma_f32_16x16x32_bf16(pa[1][c2], bv, oacc[1][dt], 0, 0, 0);
        }
      }
      __builtin_amdgcn_s_setprio(0);
    }
  }
  epilogue(qb1);
}

extern "C" void kernel_launch(void* const* d_in, const int* in_sizes, int n_in,
                              void* d_out, int out_size, void* d_ws, size_t ws_size,
                              hipStream_t stream) {
  (void)in_sizes; (void)n_in; (void)out_size; (void)d_ws; (void)ws_size;
  const float* q = (const float*)d_in[0];
  const float* k = (const float*)d_in[1];
  const float* v = (const float*)d_in[2];
  float* o = (float*)d_out;
  dim3 grid(512);    // 64 heads x 8 uniform q-tile pairs; 4 blocks/CU
  dim3 block(256);
  alibi_attn_fwd<<<grid, block, 0, stream>>>(q, k, v, o);
}